// Round 1
// baseline (752.046 us; speedup 1.0000x reference)
//
#include <hip/hip_runtime.h>
#include <hip/hip_bf16.h>

#define D128 128
#define SPLIT 2
#define CHUNK 32
#define KT2 16
#define SROWS 32
#define SKT 128
#define TOPS 8
#define FCAP 16

typedef float4 f4;

__device__ __forceinline__ void fma4(f4& a, float s, const f4& v){
  a.x = fmaf(s, v.x, a.x); a.y = fmaf(s, v.y, a.y);
  a.z = fmaf(s, v.z, a.z); a.w = fmaf(s, v.w, a.w);
}
__device__ __forceinline__ float bflo(unsigned u){ return __uint_as_float(u << 16); }
__device__ __forceinline__ float bfhi(unsigned u){ return __uint_as_float(u & 0xffff0000u); }

// rfrac[n] = positions[n] / diag(cell), padded to float4
__global__ __launch_bounds__(256) void k_prep(const float* __restrict__ pos,
    const float* __restrict__ cell, float* __restrict__ rfrac, int N){
  int i = blockIdx.x*256 + threadIdx.x;
  if(i >= N) return;
  float bx = cell[0], by = cell[4], bz = cell[8];
  f4 r; r.x = pos[i*3+0]/bx; r.y = pos[i*3+1]/by; r.z = pos[i*3+2]/bz; r.w = 0.f;
  ((f4*)rfrac)[i] = r;
}

// Structure factors: for each k, Re/Im of sum_n exp(+i 2pi rfrac.kf) * {k_vector,v_vector}[n,:]
// fp32 VALU (accuracy-critical for the softmax logits). Split over atoms, plain stores.
__global__ __launch_bounds__(256) void k_potentials(const float* __restrict__ kvec,
    const float* __restrict__ vvec, const float* __restrict__ rfrac,
    const int* __restrict__ kfwd, float* __restrict__ splitbuf, int N, int K){
  const int tid = threadIdx.x;
  const int kt = tid & 15, dgrp = tid >> 4;
  const int d0 = dgrp*8;
  const int k0 = blockIdx.x*KT2;
  const int split = blockIdx.y;
  __shared__ float kfx[KT2], kfy[KT2], kfz[KT2];
  __shared__ float ec[CHUNK][KT2], es[CHUNK][KT2];
  __shared__ float kv[CHUNK][D128], vv[CHUNK][D128];
  if(tid < KT2){
    int k = k0 + tid;
    if(k < K){ kfx[tid]=(float)kfwd[k*3]; kfy[tid]=(float)kfwd[k*3+1]; kfz[tid]=(float)kfwd[k*3+2]; }
    else { kfx[tid]=0.f; kfy[tid]=0.f; kfz[tid]=0.f; }
  }
  f4 z = make_float4(0.f,0.f,0.f,0.f);
  f4 akc0=z,akc1=z,aks0=z,aks1=z,avc0=z,avc1=z,avs0=z,avs1=z;
  const int n_per = N/SPLIT;
  const int nbeg = split*n_per;
  for(int c = nbeg; c < nbeg + n_per; c += CHUNK){
    __syncthreads();
    const f4* gk = (const f4*)(kvec + (size_t)c*D128);
    const f4* gv = (const f4*)(vvec + (size_t)c*D128);
    f4* sk = (f4*)&kv[0][0];
    f4* sv = (f4*)&vv[0][0];
    #pragma unroll
    for(int r=0; r<CHUNK*D128/4/256; r++){
      sk[tid + 256*r] = gk[tid + 256*r];
      sv[tid + 256*r] = gv[tid + 256*r];
    }
    #pragma unroll
    for(int e=0; e<CHUNK*KT2/256; e++){
      int idx = tid + e*256;
      int nl = idx >> 4, kk = idx & 15;
      f4 r = ((const f4*)rfrac)[c + nl];
      float t = r.x*kfx[kk] + r.y*kfy[kk] + r.z*kfz[kk];
      t = t - floorf(t);                  // revolutions in [0,1)
      ec[nl][kk] = cospif(2.0f*t);
      es[nl][kk] = sinpif(2.0f*t);
    }
    __syncthreads();
    #pragma unroll 4
    for(int n=0; n<CHUNK; n++){
      float e_c = ec[n][kt], e_s = es[n][kt];
      f4 a0 = *(const f4*)&kv[n][d0];
      f4 a1 = *(const f4*)&kv[n][d0+4];
      f4 b0 = *(const f4*)&vv[n][d0];
      f4 b1 = *(const f4*)&vv[n][d0+4];
      fma4(akc0, e_c, a0); fma4(akc1, e_c, a1);
      fma4(aks0, e_s, a0); fma4(aks1, e_s, a1);
      fma4(avc0, e_c, b0); fma4(avc1, e_c, b1);
      fma4(avs0, e_s, b0); fma4(avs1, e_s, b1);
    }
  }
  int k = k0 + kt;
  if(k < K){
    size_t M = (size_t)K*D128;
    float* b = splitbuf + (size_t)split*4*M + (size_t)k*D128 + d0;
    *(f4*)(b)       = akc0; *(f4*)(b+4)     = akc1;
    *(f4*)(b+M)     = aks0; *(f4*)(b+M+4)   = aks1;
    *(f4*)(b+2*M)   = avc0; *(f4*)(b+2*M+4) = avc1;
    *(f4*)(b+3*M)   = avs0; *(f4*)(b+3*M+4) = avs1;
  }
}

// Merge atom-splits; emit |k_pot| (fp32 + bf16) and Re/Im(v_pot)
__global__ __launch_bounds__(256) void k_merge(const float* __restrict__ sb,
    float* __restrict__ kabs, __hip_bfloat16* __restrict__ kabs_bf,
    float* __restrict__ vcm, float* __restrict__ vsm, int K){
  size_t M = (size_t)K*D128;
  size_t idx = (size_t)blockIdx.x*256 + threadIdx.x;
  if(idx >= M) return;
  float kc = sb[idx]     + sb[4*M + idx];
  float ks = sb[M + idx] + sb[5*M + idx];
  float vc = sb[2*M+idx] + sb[6*M + idx];
  float vs = sb[3*M+idx] + sb[7*M + idx];
  float ab = sqrtf(fmaf(kc,kc, ks*ks));
  kabs[idx] = ab;
  kabs_bf[idx] = __float2bfloat16(ab);
  vcm[idx] = vc; vsm[idx] = vs;
}

// Screen GEMM: aw[n,k] = sum_d |q|*|k_pot| (bf16-staged operand, fp32 accum).
// Emits per (row, 128-k tile) the top-8 entries within 21 of the tile max.
__global__ __launch_bounds__(256) void k_screen(const float* __restrict__ q,
    const __hip_bfloat16* __restrict__ kabs_bf, int* __restrict__ tk,
    float* __restrict__ taw, int N, int K, int NT){
  const int tid = threadIdx.x;
  const int kg = tid & 31, rg = tid >> 5;
  const int r0 = blockIdx.x*SROWS, k0 = blockIdx.y*SKT;
  __shared__ float qa[SROWS][D128];
  __shared__ uint4 ab[SKT][16];     // 8 bf16 per uint4, XOR-swizzled chunks
  __shared__ int cnt[SROWS];
  __shared__ unsigned mx[SROWS];
  if(tid < SROWS){ cnt[tid] = 0; mx[tid] = 0u; }
  {
    int row = tid >> 3, s = tid & 7;
    size_t o = ((size_t)(r0+row)*NT + blockIdx.y)*TOPS + s;
    taw[o] = -1e30f; tk[o] = -1;
  }
  #pragma unroll
  for(int i=0; i<SROWS*D128/4/256; i++){
    int idx = tid + i*256;
    int row = idx >> 5, c = idx & 31;
    f4 v = ((const f4*)(q + (size_t)(r0+row)*D128))[c];
    v.x=fabsf(v.x); v.y=fabsf(v.y); v.z=fabsf(v.z); v.w=fabsf(v.w);
    *(f4*)&qa[row][c*4] = v;
  }
  #pragma unroll
  for(int i=0; i<SKT*16/256; i++){
    int idx = tid + i*256;
    int row = idx >> 4, cc = idx & 15;
    uint4 v = make_uint4(0u,0u,0u,0u);
    if(k0 + row < K) v = ((const uint4*)(kabs_bf + (size_t)(k0+row)*D128))[cc];
    ab[row][cc ^ (row & 15)] = v;   // swizzle: conflict-free strided-row reads
  }
  __syncthreads();
  float acc[4][4];
  #pragma unroll
  for(int i=0;i<4;i++){
    #pragma unroll
    for(int j2=0;j2<4;j2++) acc[i][j2]=0.f;
  }
  for(int d=0; d<D128; d+=8){
    float qv[4][8];
    #pragma unroll
    for(int i=0;i<4;i++){
      f4 a = *(const f4*)&qa[rg*4+i][d];
      f4 b = *(const f4*)&qa[rg*4+i][d+4];
      qv[i][0]=a.x; qv[i][1]=a.y; qv[i][2]=a.z; qv[i][3]=a.w;
      qv[i][4]=b.x; qv[i][5]=b.y; qv[i][6]=b.z; qv[i][7]=b.w;
    }
    #pragma unroll
    for(int j2=0;j2<4;j2++){
      int kr = kg + 32*j2;
      uint4 av = ab[kr][(d>>3) ^ (kr & 15)];
      float f0=bflo(av.x), f1=bfhi(av.x), f2=bflo(av.y), f3=bfhi(av.y);
      float g0=bflo(av.z), g1=bfhi(av.z), g2=bflo(av.w), g3=bfhi(av.w);
      #pragma unroll
      for(int i=0;i<4;i++){
        float s = acc[i][j2];
        s = fmaf(qv[i][0], f0, s); s = fmaf(qv[i][1], f1, s);
        s = fmaf(qv[i][2], f2, s); s = fmaf(qv[i][3], f3, s);
        s = fmaf(qv[i][4], g0, s); s = fmaf(qv[i][5], g1, s);
        s = fmaf(qv[i][6], g2, s); s = fmaf(qv[i][7], g3, s);
        acc[i][j2] = s;
      }
    }
  }
  #pragma unroll
  for(int i=0;i<4;i++){
    float m4 = fmaxf(fmaxf(acc[i][0],acc[i][1]), fmaxf(acc[i][2],acc[i][3]));
    atomicMax(&mx[rg*4+i], __float_as_uint(m4));   // aw >= 0 so uint-order == float-order
  }
  __syncthreads();
  #pragma unroll
  for(int i=0;i<4;i++){
    int row = rg*4+i;
    float thresh = __uint_as_float(mx[row]) - 21.0f;
    #pragma unroll
    for(int j2=0;j2<4;j2++){
      int k = k0 + kg + 32*j2;
      float aw = acc[i][j2];
      if(k < K && aw >= thresh){
        int s = atomicAdd(&cnt[row], 1);
        if(s < TOPS){
          size_t o = ((size_t)(r0+row)*NT + blockIdx.y)*TOPS + s;
          taw[o] = aw; tk[o] = k;
        }
      }
    }
  }
}

// Per row: global max over candidates, exact fp32 logit recompute for survivors,
// softmax, and output accumulation from only those k's.
__global__ __launch_bounds__(256) void k_final(const float* __restrict__ q,
    const float* __restrict__ kabs, const float* __restrict__ vcm,
    const float* __restrict__ vsm, const float* __restrict__ rfrac,
    const int* __restrict__ kinv, const int* __restrict__ tk,
    const float* __restrict__ taw, float* __restrict__ out, int N, int K, int NT){
  const int rb = threadIdx.x >> 2;   // 0..63
  const int j  = threadIdx.x & 3;
  const int row = blockIdx.x*64 + rb;
  if(row >= N) return;
  const int NE = NT*TOPS;
  const float* trow = taw + (size_t)row*NE;
  const int*   krow = tk  + (size_t)row*NE;
  float m = -1e30f;
  for(int i=j; i<NE; i+=4) m = fmaxf(m, trow[i]);
  m = fmaxf(m, __shfl_xor(m,1)); m = fmaxf(m, __shfl_xor(m,2));
  __shared__ int lk[64][FCAP];
  __shared__ int lcnt[64];
  if(j==0) lcnt[rb] = 0;
  __syncthreads();
  for(int i=j; i<NE; i+=4){
    float aw = trow[i];
    if(aw >= m - 24.0f){
      int s = atomicAdd(&lcnt[rb], 1);
      if(s < FCAP) lk[rb][s] = krow[i];
    }
  }
  __syncthreads();
  int cn = min(lcnt[rb], FCAP);
  const float* qrow = q + (size_t)row*D128;
  float paw[FCAP];
  for(int e=0; e<cn; e++){
    int k = lk[rb][e];
    const float* ar = kabs + (size_t)k*D128;
    float p = 0.f;
    #pragma unroll
    for(int d=0; d<32; d+=4){
      int dd = j*32 + d;
      f4 qv = *(const f4*)(qrow+dd); f4 av = *(const f4*)(ar+dd);
      p = fmaf(fabsf(qv.x), av.x, p); p = fmaf(fabsf(qv.y), av.y, p);
      p = fmaf(fabsf(qv.z), av.z, p); p = fmaf(fabsf(qv.w), av.w, p);
    }
    p += __shfl_xor(p,1); p += __shfl_xor(p,2);
    paw[e] = p;
  }
  float m2 = -1e30f;
  for(int e=0;e<cn;e++) m2 = fmaxf(m2, paw[e]);
  float w[FCAP]; float Z = 0.f;
  for(int e=0;e<cn;e++){ w[e] = expf(paw[e]-m2); Z += w[e]; }
  float o[32];
  #pragma unroll
  for(int t=0;t<32;t++) o[t]=0.f;
  f4 rf = *(const f4*)(rfrac + (size_t)row*4);
  for(int e=0;e<cn;e++){
    float wn = w[e]/Z;
    if(wn < 1e-7f) continue;
    int k = lk[rb][e];
    float t = rf.x*(float)kinv[k*3] + rf.y*(float)kinv[k*3+1] + rf.z*(float)kinv[k*3+2];
    t -= floorf(t);
    float si = sinpif(2.0f*t), ci = cospif(2.0f*t);  // eik_i = cos - i sin; Re = cos*vc + sin*vs
    float wc = wn*ci, wsn = wn*si;
    const float* vcr = vcm + (size_t)k*D128 + j*32;
    const float* vsr = vsm + (size_t)k*D128 + j*32;
    #pragma unroll
    for(int d=0; d<32; d+=4){
      f4 a = *(const f4*)(vcr+d); f4 b = *(const f4*)(vsr+d);
      o[d]   = fmaf(wc, a.x, fmaf(wsn, b.x, o[d]));
      o[d+1] = fmaf(wc, a.y, fmaf(wsn, b.y, o[d+1]));
      o[d+2] = fmaf(wc, a.z, fmaf(wsn, b.z, o[d+2]));
      o[d+3] = fmaf(wc, a.w, fmaf(wsn, b.w, o[d+3]));
    }
  }
  float* orow = out + (size_t)row*D128 + j*32;
  #pragma unroll
  for(int d=0; d<32; d+=4)
    *(f4*)(orow+d) = make_float4(o[d], o[d+1], o[d+2], o[d+3]);
}

extern "C" void kernel_launch(void* const* d_in, const int* in_sizes, int n_in,
                              void* d_out, int out_size, void* d_ws, size_t ws_size,
                              hipStream_t stream){
  const float* q    = (const float*)d_in[0];
  const float* kvec = (const float*)d_in[1];
  const float* vvec = (const float*)d_in[2];
  const float* pos  = (const float*)d_in[3];
  const float* cell = (const float*)d_in[4];
  const int*   kfwd = (const int*)d_in[6];
  const int*   kinv = (const int*)d_in[7];
  const int N = in_sizes[3]/3;
  const int K = in_sizes[6]/3;
  const int NT = (K + SKT - 1)/SKT;

  float* ws = (float*)d_ws;
  size_t o = 0;
  float* rfrac    = ws + o; o += (size_t)N*4;
  float* splitbuf = ws + o; o += (size_t)SPLIT*4*K*D128;
  float* kabs     = ws + o; o += (size_t)K*D128;
  float* vcm      = ws + o; o += (size_t)K*D128;
  float* vsm      = ws + o; o += (size_t)K*D128;
  __hip_bfloat16* kabs_bf = (__hip_bfloat16*)(ws + o); o += (size_t)K*D128/2 + 4;
  float* taw      = ws + o; o += (size_t)N*NT*TOPS;
  int*   tk       = (int*)(ws + o); o += (size_t)N*NT*TOPS;
  float* out = (float*)d_out;

  k_prep<<<dim3((N+255)/256), dim3(256), 0, stream>>>(pos, cell, rfrac, N);
  k_potentials<<<dim3((K+KT2-1)/KT2, SPLIT), dim3(256), 0, stream>>>(
      kvec, vvec, rfrac, kfwd, splitbuf, N, K);
  k_merge<<<dim3((int)(((size_t)K*D128 + 255)/256)), dim3(256), 0, stream>>>(
      splitbuf, kabs, kabs_bf, vcm, vsm, K);
  k_screen<<<dim3(N/SROWS, NT), dim3(256), 0, stream>>>(q, kabs_bf, tk, taw, N, K, NT);
  k_final<<<dim3((N+63)/64), dim3(256), 0, stream>>>(
      q, kabs, vcm, vsm, rfrac, kinv, tk, taw, out, N, K, NT);
}

// Round 3
// 441.812 us; speedup vs baseline: 1.7022x; 1.7022x over previous
//
#include <hip/hip_runtime.h>
#include <hip/hip_bf16.h>

#define D128 128
#define NSPLIT 2
#define KT 32
#define SROWS 32
#define SKT 128
#define TOPS 8
#define FCAP 16

typedef float4 f4;
typedef __attribute__((ext_vector_type(8))) short short8v;
typedef __attribute__((ext_vector_type(4))) float f32x4;

__device__ __forceinline__ float bflo(unsigned u){ return __uint_as_float(u << 16); }
__device__ __forceinline__ float bfhi(unsigned u){ return __uint_as_float(u & 0xffff0000u); }
__device__ __forceinline__ unsigned short f2bu(float x){
  __hip_bfloat16 h = __float2bfloat16(x);
  return *(unsigned short*)&h;
}
__device__ __forceinline__ float bu2f(unsigned short u){
  return __uint_as_float(((unsigned)u) << 16);
}

#define GLDS16(gp, lp) __builtin_amdgcn_global_load_lds( \
    (const __attribute__((address_space(1))) unsigned int*)(const void*)(gp), \
    (__attribute__((address_space(3))) unsigned int*)(lp), 16, 0, 0)

// rfrac[n] = positions[n] / diag(cell), padded to float4
__global__ __launch_bounds__(256) void k_prep(const float* __restrict__ pos,
    const float* __restrict__ cell, float* __restrict__ rfrac, int N){
  int i = blockIdx.x*256 + threadIdx.x;
  if(i >= N) return;
  float bx = cell[0], by = cell[4], bz = cell[8];
  f4 r; r.x = pos[i*3+0]/bx; r.y = pos[i*3+1]/by; r.z = pos[i*3+2]/bz; r.w = 0.f;
  ((f4*)rfrac)[i] = r;
}

// Transpose + bf16-split k_vector/v_vector into [d][atom] global layout:
// kvhT/kvlT = hi/lo split of k_vector (for 3-MFMA near-fp32 product),
// vvhT = single bf16 of v_vector.
__global__ __launch_bounds__(256) void k_cvt(const float* __restrict__ kvec,
    const float* __restrict__ vvec, unsigned short* __restrict__ kvhT,
    unsigned short* __restrict__ kvlT, unsigned short* __restrict__ vvhT, int N){
  __shared__ float sk[32][132], sv[32][132];
  const int tid = threadIdx.x;
  const int c0 = blockIdx.x*32;
  #pragma unroll
  for(int i=0;i<4;i++){
    int idx = tid + i*256;            // 1024 f4-loads: 32 atoms x 32 quads
    int a = idx >> 5, fq = idx & 31;
    f4 v = ((const f4*)(kvec + (size_t)(c0+a)*D128))[fq];
    *(f4*)&sk[a][fq*4] = v;
    f4 u = ((const f4*)(vvec + (size_t)(c0+a)*D128))[fq];
    *(f4*)&sv[a][fq*4] = u;
  }
  __syncthreads();
  #pragma unroll
  for(int i=0;i<4;i++){
    int idx = tid + i*256;            // 1024 quad-items: 128 d x 8 atom-quads
    int d = idx >> 3, aq = idx & 7;
    size_t ob = (size_t)d*N + c0 + aq*4;
    ushort4 h, l, vh;
    float x0 = sk[aq*4+0][d], x1 = sk[aq*4+1][d], x2 = sk[aq*4+2][d], x3 = sk[aq*4+3][d];
    h.x = f2bu(x0); h.y = f2bu(x1); h.z = f2bu(x2); h.w = f2bu(x3);
    l.x = f2bu(x0 - bu2f(h.x)); l.y = f2bu(x1 - bu2f(h.y));
    l.z = f2bu(x2 - bu2f(h.z)); l.w = f2bu(x3 - bu2f(h.w));
    vh.x = f2bu(sv[aq*4+0][d]); vh.y = f2bu(sv[aq*4+1][d]);
    vh.z = f2bu(sv[aq*4+2][d]); vh.w = f2bu(sv[aq*4+3][d]);
    *(ushort4*)(kvhT + ob) = h;
    *(ushort4*)(kvlT + ob) = l;
    *(ushort4*)(vvhT + ob) = vh;
  }
}

// MFMA structure factors. Block: 32 k-vectors x full D=128, half the atoms
// (split along grid.y). 8 waves, wave w owns d-tile [w*16, w*16+16).
// Per 32-atom chunk: stage B (bf16, [d][atom]) via global_load_lds;
// generate E = exp(i*2pi*rfrac.k) hi/lo bf16 splits in LDS; 16 MFMAs/wave.
__global__ __launch_bounds__(512) void k_pot_mfma(
    const unsigned short* __restrict__ kvhT, const unsigned short* __restrict__ kvlT,
    const unsigned short* __restrict__ vvhT, const float* __restrict__ rfrac,
    const int* __restrict__ kfwd, float* __restrict__ splitbuf, int N, int K){
  const int tid = threadIdx.x;
  const int k0 = blockIdx.x*KT;
  const int split = blockIdx.y;
  const int half = N/NSPLIT;
  const int abase = split*half;
  __shared__ float kfx[KT], kfy[KT], kfz[KT];
  __shared__ unsigned short Ae[4][KT][32];    // [ech,ecl,esh,esl][k][atom]
  __shared__ unsigned short Bl[3][D128][32];  // [kvh,kvl,vvh][d][atom]
  if(tid < KT){
    int k = k0 + tid;
    if(k < K){ kfx[tid]=(float)kfwd[3*k]; kfy[tid]=(float)kfwd[3*k+1]; kfz[tid]=(float)kfwd[3*k+2]; }
    else { kfx[tid]=0.f; kfy[tid]=0.f; kfz[tid]=0.f; }
  }
  const int w = tid >> 6, l = tid & 63, l15 = l & 15, g = l >> 4;
  f32x4 acc[2][4];   // [ksub][kc,ks,vc,vs]
  #pragma unroll
  for(int i=0;i<2;i++)
    #pragma unroll
    for(int j=0;j<4;j++)
      acc[i][j] = (f32x4){0.f,0.f,0.f,0.f};
  const int a = tid & 31, rq = tid >> 5;      // E-gen mapping
  for(int ch=0; ch<half/32; ch++){
    const int c0a = abase + ch*32;
    __syncthreads();
    {   // stage B: wave w covers 16 d-rows per array
      int row = w*16 + (l >> 2);
      size_t goff = (size_t)row*N + c0a + (l & 3)*8;
      GLDS16(kvhT + goff, &Bl[0][w*16][0]);
      GLDS16(kvlT + goff, &Bl[1][w*16][0]);
      GLDS16(vvhT + goff, &Bl[2][w*16][0]);
    }
    {   // E-gen: 2 k's per thread for one atom
      f4 rf = ((const f4*)rfrac)[c0a + a];
      #pragma unroll
      for(int rr=0; rr<2; rr++){
        int r = rq*2 + rr;
        float t = rf.x*kfx[r] + rf.y*kfy[r] + rf.z*kfz[r];
        t -= floorf(t);
        float cv = cospif(2.0f*t), sv = sinpif(2.0f*t);
        unsigned short chb = f2bu(cv);
        unsigned short clb = f2bu(cv - bu2f(chb));
        unsigned short shb = f2bu(sv);
        unsigned short slb = f2bu(sv - bu2f(shb));
        Ae[0][r][a] = chb; Ae[1][r][a] = clb; Ae[2][r][a] = shb; Ae[3][r][a] = slb;
      }
    }
    __syncthreads();
    short8v eA[2][4];
    #pragma unroll
    for(int ks=0; ks<2; ks++)
      #pragma unroll
      for(int ar=0; ar<4; ar++)
        eA[ks][ar] = *(const short8v*)&Ae[ar][ks*16 + l15][g*8];
    short8v bKh = *(const short8v*)&Bl[0][w*16 + l15][g*8];
    short8v bKl = *(const short8v*)&Bl[1][w*16 + l15][g*8];
    short8v bVh = *(const short8v*)&Bl[2][w*16 + l15][g*8];
    #pragma unroll
    for(int ks=0; ks<2; ks++){
      acc[ks][0] = __builtin_amdgcn_mfma_f32_16x16x32_bf16(eA[ks][0], bKh, acc[ks][0], 0,0,0);
      acc[ks][1] = __builtin_amdgcn_mfma_f32_16x16x32_bf16(eA[ks][2], bKh, acc[ks][1], 0,0,0);
      acc[ks][2] = __builtin_amdgcn_mfma_f32_16x16x32_bf16(eA[ks][0], bVh, acc[ks][2], 0,0,0);
      acc[ks][3] = __builtin_amdgcn_mfma_f32_16x16x32_bf16(eA[ks][2], bVh, acc[ks][3], 0,0,0);
      acc[ks][0] = __builtin_amdgcn_mfma_f32_16x16x32_bf16(eA[ks][0], bKl, acc[ks][0], 0,0,0);
      acc[ks][1] = __builtin_amdgcn_mfma_f32_16x16x32_bf16(eA[ks][2], bKl, acc[ks][1], 0,0,0);
      acc[ks][0] = __builtin_amdgcn_mfma_f32_16x16x32_bf16(eA[ks][1], bKh, acc[ks][0], 0,0,0);
      acc[ks][1] = __builtin_amdgcn_mfma_f32_16x16x32_bf16(eA[ks][3], bKh, acc[ks][1], 0,0,0);
    }
  }
  // epilogue: C/D layout col=lane&15 (d), row=(lane>>4)*4+reg (k)
  size_t M = (size_t)K*D128;
  #pragma unroll
  for(int ks=0; ks<2; ks++){
    #pragma unroll
    for(int reg=0; reg<4; reg++){
      int k = k0 + ks*16 + g*4 + reg;
      if(k < K){
        int d = w*16 + l15;
        size_t base = (size_t)split*4*M + (size_t)k*D128 + d;
        splitbuf[base]       = acc[ks][0][reg];
        splitbuf[base + M]   = acc[ks][1][reg];
        splitbuf[base + 2*M] = acc[ks][2][reg];
        splitbuf[base + 3*M] = acc[ks][3][reg];
      }
    }
  }
}

// Merge atom-splits; emit |k_pot| (fp32 + bf16) and Re/Im(v_pot)
__global__ __launch_bounds__(256) void k_merge(const float* __restrict__ sb,
    float* __restrict__ kabs, __hip_bfloat16* __restrict__ kabs_bf,
    float* __restrict__ vcm, float* __restrict__ vsm, int K){
  size_t M = (size_t)K*D128;
  size_t idx = (size_t)blockIdx.x*256 + threadIdx.x;
  if(idx >= M) return;
  float kc = sb[idx]     + sb[4*M + idx];
  float ks = sb[M + idx] + sb[5*M + idx];
  float vc = sb[2*M+idx] + sb[6*M + idx];
  float vs = sb[3*M+idx] + sb[7*M + idx];
  float ab = sqrtf(fmaf(kc,kc, ks*ks));
  kabs[idx] = ab;
  kabs_bf[idx] = __float2bfloat16(ab);
  vcm[idx] = vc; vsm[idx] = vs;
}

// Screen GEMM: aw[n,k] = sum_d |q|*|k_pot| (bf16-staged operand, fp32 accum).
// Emits per (row, 128-k tile) the top-8 entries within 21 of the tile max.
__global__ __launch_bounds__(256) void k_screen(const float* __restrict__ q,
    const __hip_bfloat16* __restrict__ kabs_bf, int* __restrict__ tk,
    float* __restrict__ taw, int N, int K, int NT){
  const int tid = threadIdx.x;
  const int kg = tid & 31, rg = tid >> 5;
  const int r0 = blockIdx.x*SROWS, k0 = blockIdx.y*SKT;
  __shared__ float qa[SROWS][D128];
  __shared__ uint4 ab[SKT][16];
  __shared__ int cnt[SROWS];
  __shared__ unsigned mx[SROWS];
  if(tid < SROWS){ cnt[tid] = 0; mx[tid] = 0u; }
  {
    int row = tid >> 3, s = tid & 7;
    size_t o = ((size_t)(r0+row)*NT + blockIdx.y)*TOPS + s;
    taw[o] = -1e30f; tk[o] = -1;
  }
  #pragma unroll
  for(int i=0; i<SROWS*D128/4/256; i++){
    int idx = tid + i*256;
    int row = idx >> 5, c = idx & 31;
    f4 v = ((const f4*)(q + (size_t)(r0+row)*D128))[c];
    v.x=fabsf(v.x); v.y=fabsf(v.y); v.z=fabsf(v.z); v.w=fabsf(v.w);
    *(f4*)&qa[row][c*4] = v;
  }
  #pragma unroll
  for(int i=0; i<SKT*16/256; i++){
    int idx = tid + i*256;
    int row = idx >> 4, cc = idx & 15;
    uint4 v = make_uint4(0u,0u,0u,0u);
    if(k0 + row < K) v = ((const uint4*)(kabs_bf + (size_t)(k0+row)*D128))[cc];
    ab[row][cc ^ (row & 15)] = v;
  }
  __syncthreads();
  float acc[4][4];
  #pragma unroll
  for(int i=0;i<4;i++){
    #pragma unroll
    for(int j2=0;j2<4;j2++) acc[i][j2]=0.f;
  }
  for(int d=0; d<D128; d+=8){
    float qv[4][8];
    #pragma unroll
    for(int i=0;i<4;i++){
      f4 a = *(const f4*)&qa[rg*4+i][d];
      f4 b = *(const f4*)&qa[rg*4+i][d+4];
      qv[i][0]=a.x; qv[i][1]=a.y; qv[i][2]=a.z; qv[i][3]=a.w;
      qv[i][4]=b.x; qv[i][5]=b.y; qv[i][6]=b.z; qv[i][7]=b.w;
    }
    #pragma unroll
    for(int j2=0;j2<4;j2++){
      int kr = kg + 32*j2;
      uint4 av = ab[kr][(d>>3) ^ (kr & 15)];
      float f0=bflo(av.x), f1=bfhi(av.x), f2=bflo(av.y), f3=bfhi(av.y);
      float g0=bflo(av.z), g1=bfhi(av.z), g2=bflo(av.w), g3=bfhi(av.w);
      #pragma unroll
      for(int i=0;i<4;i++){
        float s = acc[i][j2];
        s = fmaf(qv[i][0], f0, s); s = fmaf(qv[i][1], f1, s);
        s = fmaf(qv[i][2], f2, s); s = fmaf(qv[i][3], f3, s);
        s = fmaf(qv[i][4], g0, s); s = fmaf(qv[i][5], g1, s);
        s = fmaf(qv[i][6], g2, s); s = fmaf(qv[i][7], g3, s);
        acc[i][j2] = s;
      }
    }
  }
  #pragma unroll
  for(int i=0;i<4;i++){
    float m4 = fmaxf(fmaxf(acc[i][0],acc[i][1]), fmaxf(acc[i][2],acc[i][3]));
    atomicMax(&mx[rg*4+i], __float_as_uint(m4));
  }
  __syncthreads();
  #pragma unroll
  for(int i=0;i<4;i++){
    int row = rg*4+i;
    float thresh = __uint_as_float(mx[row]) - 21.0f;
    #pragma unroll
    for(int j2=0;j2<4;j2++){
      int k = k0 + kg + 32*j2;
      float aw = acc[i][j2];
      if(k < K && aw >= thresh){
        int s = atomicAdd(&cnt[row], 1);
        if(s < TOPS){
          size_t o = ((size_t)(r0+row)*NT + blockIdx.y)*TOPS + s;
          taw[o] = aw; tk[o] = k;
        }
      }
    }
  }
}

// Per row: global max over candidates, exact fp32 logit recompute for survivors,
// softmax, and output accumulation from only those k's.
__global__ __launch_bounds__(256) void k_final(const float* __restrict__ q,
    const float* __restrict__ kabs, const float* __restrict__ vcm,
    const float* __restrict__ vsm, const float* __restrict__ rfrac,
    const int* __restrict__ kinv, const int* __restrict__ tk,
    const float* __restrict__ taw, float* __restrict__ out, int N, int K, int NT){
  const int rb = threadIdx.x >> 2;
  const int j  = threadIdx.x & 3;
  const int row = blockIdx.x*64 + rb;
  if(row >= N) return;
  const int NE = NT*TOPS;
  const float* trow = taw + (size_t)row*NE;
  const int*   krow = tk  + (size_t)row*NE;
  float m = -1e30f;
  for(int i=j; i<NE; i+=4) m = fmaxf(m, trow[i]);
  m = fmaxf(m, __shfl_xor(m,1)); m = fmaxf(m, __shfl_xor(m,2));
  __shared__ int lk[64][FCAP];
  __shared__ int lcnt[64];
  if(j==0) lcnt[rb] = 0;
  __syncthreads();
  for(int i=j; i<NE; i+=4){
    float aw = trow[i];
    if(aw >= m - 24.0f){
      int s = atomicAdd(&lcnt[rb], 1);
      if(s < FCAP) lk[rb][s] = krow[i];
    }
  }
  __syncthreads();
  int cn = min(lcnt[rb], FCAP);
  const float* qrow = q + (size_t)row*D128;
  float paw[FCAP];
  for(int e=0; e<cn; e++){
    int k = lk[rb][e];
    const float* ar = kabs + (size_t)k*D128;
    float p = 0.f;
    #pragma unroll
    for(int d=0; d<32; d+=4){
      int dd = j*32 + d;
      f4 qv = *(const f4*)(qrow+dd); f4 av = *(const f4*)(ar+dd);
      p = fmaf(fabsf(qv.x), av.x, p); p = fmaf(fabsf(qv.y), av.y, p);
      p = fmaf(fabsf(qv.z), av.z, p); p = fmaf(fabsf(qv.w), av.w, p);
    }
    p += __shfl_xor(p,1); p += __shfl_xor(p,2);
    paw[e] = p;
  }
  float m2 = -1e30f;
  for(int e=0;e<cn;e++) m2 = fmaxf(m2, paw[e]);
  float w[FCAP]; float Z = 0.f;
  for(int e=0;e<cn;e++){ w[e] = expf(paw[e]-m2); Z += w[e]; }
  float o[32];
  #pragma unroll
  for(int t=0;t<32;t++) o[t]=0.f;
  f4 rf = *(const f4*)(rfrac + (size_t)row*4);
  for(int e=0;e<cn;e++){
    float wn = w[e]/Z;
    if(wn < 1e-7f) continue;
    int k = lk[rb][e];
    float t = rf.x*(float)kinv[k*3] + rf.y*(float)kinv[k*3+1] + rf.z*(float)kinv[k*3+2];
    t -= floorf(t);
    float si = sinpif(2.0f*t), ci = cospif(2.0f*t);
    float wc = wn*ci, wsn = wn*si;
    const float* vcr = vcm + (size_t)k*D128 + j*32;
    const float* vsr = vsm + (size_t)k*D128 + j*32;
    #pragma unroll
    for(int d=0; d<32; d+=4){
      f4 a2 = *(const f4*)(vcr+d); f4 b2 = *(const f4*)(vsr+d);
      o[d]   = fmaf(wc, a2.x, fmaf(wsn, b2.x, o[d]));
      o[d+1] = fmaf(wc, a2.y, fmaf(wsn, b2.y, o[d+1]));
      o[d+2] = fmaf(wc, a2.z, fmaf(wsn, b2.z, o[d+2]));
      o[d+3] = fmaf(wc, a2.w, fmaf(wsn, b2.w, o[d+3]));
    }
  }
  float* orow = out + (size_t)row*D128 + j*32;
  #pragma unroll
  for(int d=0; d<32; d+=4)
    *(f4*)(orow+d) = make_float4(o[d], o[d+1], o[d+2], o[d+3]);
}

extern "C" void kernel_launch(void* const* d_in, const int* in_sizes, int n_in,
                              void* d_out, int out_size, void* d_ws, size_t ws_size,
                              hipStream_t stream){
  const float* q    = (const float*)d_in[0];
  const float* kvec = (const float*)d_in[1];
  const float* vvec = (const float*)d_in[2];
  const float* pos  = (const float*)d_in[3];
  const float* cell = (const float*)d_in[4];
  const int*   kfwd = (const int*)d_in[6];
  const int*   kinv = (const int*)d_in[7];
  const int N = in_sizes[3]/3;
  const int K = in_sizes[6]/3;
  const int NT = (K + SKT - 1)/SKT;
  const int KTILES = (K + KT - 1)/KT;

  float* ws = (float*)d_ws;
  size_t o = 0;
  float* rfrac    = ws + o; o += (size_t)N*4;
  float* splitbuf = ws + o; o += (size_t)NSPLIT*4*K*D128;
  float* kabs     = ws + o; o += (size_t)K*D128;
  float* vcm      = ws + o; o += (size_t)K*D128;
  float* vsm      = ws + o; o += (size_t)K*D128;
  __hip_bfloat16* kabs_bf = (__hip_bfloat16*)(ws + o); o += (size_t)K*D128/2 + 4;
  float* taw      = ws + o; o += (size_t)N*NT*TOPS;
  int*   tk       = (int*)(ws + o); o += (size_t)N*NT*TOPS;
  unsigned short* kvhT = (unsigned short*)(ws + o); o += (size_t)D128*N/2;
  unsigned short* kvlT = (unsigned short*)(ws + o); o += (size_t)D128*N/2;
  unsigned short* vvhT = (unsigned short*)(ws + o); o += (size_t)D128*N/2;
  float* out = (float*)d_out;

  k_prep<<<dim3((N+255)/256), dim3(256), 0, stream>>>(pos, cell, rfrac, N);
  k_cvt<<<dim3(N/32), dim3(256), 0, stream>>>(kvec, vvec, kvhT, kvlT, vvhT, N);
  k_pot_mfma<<<dim3(KTILES, NSPLIT), dim3(512), 0, stream>>>(
      kvhT, kvlT, vvhT, rfrac, kfwd, splitbuf, N, K);
  k_merge<<<dim3((int)(((size_t)K*D128 + 255)/256)), dim3(256), 0, stream>>>(
      splitbuf, kabs, kabs_bf, vcm, vsm, K);
  k_screen<<<dim3(N/SROWS, NT), dim3(256), 0, stream>>>(q, kabs_bf, tk, taw, N, K, NT);
  k_final<<<dim3((N+63)/64), dim3(256), 0, stream>>>(
      q, kabs, vcm, vsm, rfrac, kinv, tk, taw, out, N, K, NT);
}

// Round 5
// 271.752 us; speedup vs baseline: 2.7674x; 1.6258x over previous
//
#include <hip/hip_runtime.h>
#include <hip/hip_bf16.h>

#define D128 128
#define NSPLIT 4
#define KT 32
#define SNR 32
#define SKT 128
#define TOPS 8
#define FCAP 16

typedef float4 f4;
typedef __attribute__((ext_vector_type(8))) short short8v;
typedef __attribute__((ext_vector_type(4))) float f32x4;

__device__ __forceinline__ unsigned short f2bu(float x){
  __hip_bfloat16 h = __float2bfloat16(x);
  return *(unsigned short*)&h;
}
__device__ __forceinline__ float bu2f(unsigned short u){
  return __uint_as_float(((unsigned)u) << 16);
}

#define GLDS16(gp, lp) __builtin_amdgcn_global_load_lds( \
    (const __attribute__((address_space(1))) unsigned int*)(const void*)(gp), \
    (__attribute__((address_space(3))) unsigned int*)(lp), 16, 0, 0)

// rfrac[n] = positions[n] / diag(cell), padded to float4
__global__ __launch_bounds__(256) void k_prep(const float* __restrict__ pos,
    const float* __restrict__ cell, float* __restrict__ rfrac, int N){
  int i = blockIdx.x*256 + threadIdx.x;
  if(i >= N) return;
  float bx = cell[0], by = cell[4], bz = cell[8];
  f4 r; r.x = pos[i*3+0]/bx; r.y = pos[i*3+1]/by; r.z = pos[i*3+2]/bz; r.w = 0.f;
  ((f4*)rfrac)[i] = r;
}

// zero the pot4 accumulator (ws is poisoned 0xAA before every launch)
__global__ __launch_bounds__(256) void k_zero(float* __restrict__ p, int total){
  int i = blockIdx.x*256 + threadIdx.x;
  int stride = gridDim.x*256;
  for(; i < total; i += stride) p[i] = 0.f;
}

// Transpose + bf16-split k_vector/v_vector into [d][atom] layout (hi/lo split for
// k_vector, single bf16 for v_vector), and emit |q| bf16 row-major with the
// G4 chunk-XOR swizzle (chunk ^= row&7) baked into the global layout.
__global__ __launch_bounds__(256) void k_cvt(const float* __restrict__ q,
    const float* __restrict__ kvec, const float* __restrict__ vvec,
    unsigned short* __restrict__ kvhT, unsigned short* __restrict__ kvlT,
    unsigned short* __restrict__ vvhT, unsigned short* __restrict__ qa_bf, int N){
  __shared__ float sk[32][132], sv[32][132];
  const int tid = threadIdx.x;
  const int c0 = blockIdx.x*32;
  // |q| bf16, swizzled chunks (no LDS needed)
  #pragma unroll
  for(int i=0;i<2;i++){
    int idx = tid + i*256;            // 512 tasks: 32 rows x 16 chunks
    int row = idx >> 4, c = idx & 15;
    const float* src = q + (size_t)(c0+row)*D128 + c*8;
    f4 v0 = *(const f4*)src, v1 = *(const f4*)(src+4);
    uint4 o;
    o.x = (unsigned)f2bu(fabsf(v0.x)) | ((unsigned)f2bu(fabsf(v0.y))<<16);
    o.y = (unsigned)f2bu(fabsf(v0.z)) | ((unsigned)f2bu(fabsf(v0.w))<<16);
    o.z = (unsigned)f2bu(fabsf(v1.x)) | ((unsigned)f2bu(fabsf(v1.y))<<16);
    o.w = (unsigned)f2bu(fabsf(v1.z)) | ((unsigned)f2bu(fabsf(v1.w))<<16);
    *(uint4*)(qa_bf + (size_t)(c0+row)*D128 + ((c ^ (row&7))<<3)) = o;
  }
  #pragma unroll
  for(int i=0;i<4;i++){
    int idx = tid + i*256;            // 1024 f4-loads: 32 atoms x 32 quads
    int a = idx >> 5, fq = idx & 31;
    f4 v = ((const f4*)(kvec + (size_t)(c0+a)*D128))[fq];
    *(f4*)&sk[a][fq*4] = v;
    f4 u = ((const f4*)(vvec + (size_t)(c0+a)*D128))[fq];
    *(f4*)&sv[a][fq*4] = u;
  }
  __syncthreads();
  #pragma unroll
  for(int i=0;i<4;i++){
    int idx = tid + i*256;            // 1024 quad-items: 128 d x 8 atom-quads
    int d = idx >> 3, aq = idx & 7;
    size_t ob = (size_t)d*N + c0 + aq*4;
    ushort4 h, l, vh;
    float x0 = sk[aq*4+0][d], x1 = sk[aq*4+1][d], x2 = sk[aq*4+2][d], x3 = sk[aq*4+3][d];
    h.x = f2bu(x0); h.y = f2bu(x1); h.z = f2bu(x2); h.w = f2bu(x3);
    l.x = f2bu(x0 - bu2f(h.x)); l.y = f2bu(x1 - bu2f(h.y));
    l.z = f2bu(x2 - bu2f(h.z)); l.w = f2bu(x3 - bu2f(h.w));
    vh.x = f2bu(sv[aq*4+0][d]); vh.y = f2bu(sv[aq*4+1][d]);
    vh.z = f2bu(sv[aq*4+2][d]); vh.w = f2bu(sv[aq*4+3][d]);
    *(ushort4*)(kvhT + ob) = h;
    *(ushort4*)(kvlT + ob) = l;
    *(ushort4*)(vvhT + ob) = vh;
  }
}

// MFMA structure factors, 2-phase pipelined, LDS chunk-XOR swizzled.
// Block: 32 k x D=128, N/NSPLIT atoms. 8 waves, wave w owns d-tile [w*16,+16).
// Partial sums accumulated into pot4 via device-scope atomicAdd (4 adds/address).
__global__ __launch_bounds__(512) void k_pot_mfma(
    const unsigned short* __restrict__ kvhT, const unsigned short* __restrict__ kvlT,
    const unsigned short* __restrict__ vvhT, const float* __restrict__ rfrac,
    const int* __restrict__ kfwd, float* __restrict__ pot4, int N, int K){
  const int tid = threadIdx.x;
  const int k0 = blockIdx.x*KT;
  const int split = blockIdx.y;
  const int part = N/NSPLIT;
  const int abase = split*part;
  __shared__ unsigned short Ae[2][4][KT][32];    // [buf][ech,ecl,esh,esl][k][atom-swz]
  __shared__ unsigned short Bl[2][3][D128][32];  // [buf][kvh,kvl,vvh][d][atom-swz]
  const int w = tid >> 6, l = tid & 63, l15 = l & 15, g = l >> 4;
  const int a = tid & 31, rq = tid >> 5;
  float kfr[2][3];
  {
    int r0 = min(k0 + rq*2,     K-1);
    int r1 = min(k0 + rq*2 + 1, K-1);
    kfr[0][0] = (float)kfwd[3*r0]; kfr[0][1] = (float)kfwd[3*r0+1]; kfr[0][2] = (float)kfwd[3*r0+2];
    kfr[1][0] = (float)kfwd[3*r1]; kfr[1][1] = (float)kfwd[3*r1+1]; kfr[1][2] = (float)kfwd[3*r1+2];
  }
  f32x4 acc[2][4];   // [ksub][kc,ks,vc,vs]
  #pragma unroll
  for(int i=0;i<2;i++)
    #pragma unroll
    for(int j=0;j<4;j++)
      acc[i][j] = (f32x4){0.f,0.f,0.f,0.f};
  const int rowS = w*16 + (l >> 2);                 // staging row (d)
  const int csrc = (((l & 3) ^ ((l >> 3) & 3)))*8;  // source chunk, inv-swizzle
  const int cA   = (g ^ ((l15 >> 1) & 3))*8;        // read chunk (swizzled)

  auto stage = [&](int buf, int c0a){
    size_t goff = (size_t)rowS*N + c0a + csrc;
    GLDS16(kvhT + goff, &Bl[buf][0][w*16][0]);
    GLDS16(kvlT + goff, &Bl[buf][1][w*16][0]);
    GLDS16(vvhT + goff, &Bl[buf][2][w*16][0]);
  };
  auto egen = [&](int buf, int c0a){
    f4 rf = ((const f4*)rfrac)[c0a + a];
    #pragma unroll
    for(int rr=0; rr<2; rr++){
      int r = rq*2 + rr;
      float t = rf.x*kfr[rr][0] + rf.y*kfr[rr][1] + rf.z*kfr[rr][2];
      t -= floorf(t);
      float cv = cospif(2.0f*t), sv = sinpif(2.0f*t);
      unsigned short chb = f2bu(cv);
      unsigned short clb = f2bu(cv - bu2f(chb));
      unsigned short shb = f2bu(sv);
      unsigned short slb = f2bu(sv - bu2f(shb));
      int cp = (((a>>3) ^ ((r>>1)&3)) << 3) | (a & 7);
      Ae[buf][0][r][cp] = chb; Ae[buf][1][r][cp] = clb;
      Ae[buf][2][r][cp] = shb; Ae[buf][3][r][cp] = slb;
    }
  };

  stage(0, abase); egen(0, abase);
  __syncthreads();
  const int nch = part/32;
  for(int ch=0; ch<nch; ch++){
    int cur = ch & 1;
    if(ch+1 < nch){ stage(cur^1, abase + (ch+1)*32); egen(cur^1, abase + (ch+1)*32); }
    short8v eA[2][4];
    #pragma unroll
    for(int ks=0; ks<2; ks++)
      #pragma unroll
      for(int ar=0; ar<4; ar++)
        eA[ks][ar] = *(const short8v*)&Ae[cur][ar][ks*16 + l15][cA];
    short8v bKh = *(const short8v*)&Bl[cur][0][w*16 + l15][cA];
    short8v bKl = *(const short8v*)&Bl[cur][1][w*16 + l15][cA];
    short8v bVh = *(const short8v*)&Bl[cur][2][w*16 + l15][cA];
    #pragma unroll
    for(int ks=0; ks<2; ks++){
      acc[ks][0] = __builtin_amdgcn_mfma_f32_16x16x32_bf16(eA[ks][0], bKh, acc[ks][0], 0,0,0);
      acc[ks][1] = __builtin_amdgcn_mfma_f32_16x16x32_bf16(eA[ks][2], bKh, acc[ks][1], 0,0,0);
      acc[ks][2] = __builtin_amdgcn_mfma_f32_16x16x32_bf16(eA[ks][0], bVh, acc[ks][2], 0,0,0);
      acc[ks][3] = __builtin_amdgcn_mfma_f32_16x16x32_bf16(eA[ks][2], bVh, acc[ks][3], 0,0,0);
      acc[ks][0] = __builtin_amdgcn_mfma_f32_16x16x32_bf16(eA[ks][0], bKl, acc[ks][0], 0,0,0);
      acc[ks][1] = __builtin_amdgcn_mfma_f32_16x16x32_bf16(eA[ks][2], bKl, acc[ks][1], 0,0,0);
      acc[ks][0] = __builtin_amdgcn_mfma_f32_16x16x32_bf16(eA[ks][1], bKh, acc[ks][0], 0,0,0);
      acc[ks][1] = __builtin_amdgcn_mfma_f32_16x16x32_bf16(eA[ks][3], bKh, acc[ks][1], 0,0,0);
    }
    __syncthreads();
  }
  // epilogue: C/D layout col=lane&15 (d), row=(lane>>4)*4+reg (k)
  size_t M = (size_t)K*D128;
  #pragma unroll
  for(int ks=0; ks<2; ks++){
    #pragma unroll
    for(int reg=0; reg<4; reg++){
      int k = k0 + ks*16 + g*4 + reg;
      if(k < K){
        int d = w*16 + l15;
        size_t base = (size_t)k*D128 + d;
        atomicAdd(&pot4[base],       acc[ks][0][reg]);
        atomicAdd(&pot4[base + M],   acc[ks][1][reg]);
        atomicAdd(&pot4[base + 2*M], acc[ks][2][reg]);
        atomicAdd(&pot4[base + 3*M], acc[ks][3][reg]);
      }
    }
  }
}

// Emit |k_pot| (fp32 exact + bf16 swizzled) and Re/Im(v_pot); zero the
// kabs_swz padding rows k in [K, KPAD) so the screen never sees poison.
__global__ __launch_bounds__(256) void k_merge(const float* __restrict__ pot4,
    float* __restrict__ kabs, unsigned short* __restrict__ kabs_swz,
    float* __restrict__ vcm, float* __restrict__ vsm, int K, int KPAD){
  size_t M = (size_t)K*D128;
  size_t idx = (size_t)blockIdx.x*256 + threadIdx.x;
  if(idx >= (size_t)KPAD*D128) return;
  int k = (int)(idx >> 7), d = (int)(idx & 127);
  size_t sw = (size_t)k*D128 + ((((d>>3) ^ (k&7))<<3) | (d&7));
  if(idx < M){
    float kc = pot4[idx], ks_ = pot4[M+idx], vc = pot4[2*M+idx], vs = pot4[3*M+idx];
    float ab = sqrtf(fmaf(kc,kc, ks_*ks_));
    kabs[idx] = ab;
    vcm[idx] = vc; vsm[idx] = vs;
    kabs_swz[sw] = f2bu(ab);
  } else {
    kabs_swz[sw] = 0;
  }
}

// Screen GEMM via bf16 MFMA: aw[n,k] = sum_d |q|*|k_pot|.
// Block: 32 n-rows x 128 k. 4 waves, wave w owns k-block [w*32,+32).
// Emits per (row, 128-k tile) the top-8 entries within 21 of the tile max.
__global__ __launch_bounds__(256) void k_screen(
    const unsigned short* __restrict__ qa_bf, const unsigned short* __restrict__ kabs_swz,
    int* __restrict__ tk, float* __restrict__ taw, int N, int K, int NT){
  const int tid = threadIdx.x;
  const int w = tid >> 6, l = tid & 63, l15 = l & 15, g = l >> 4;
  const int n0 = blockIdx.x*SNR;
  const int ty = blockIdx.y;
  const int k0 = ty*SKT;
  __shared__ unsigned short Kb[SKT][D128];
  __shared__ unsigned short Qa[SNR][D128];
  __shared__ int cnt[SNR];
  __shared__ unsigned mx[SNR];
  if(tid < SNR){ cnt[tid] = 0; mx[tid] = 0u; }
  {
    int row = tid >> 3, s = tid & 7;
    size_t o = ((size_t)(n0+row)*NT + ty)*TOPS + s;
    taw[o] = -1e30f; tk[o] = -1;
  }
  // stage Kb (128 rows x 16 chunks = 2048 slots), already swizzled in global
  #pragma unroll
  for(int j=0;j<8;j++){
    int sbase = w*512 + j*64;
    GLDS16(kabs_swz + (size_t)k0*D128 + (size_t)(sbase + l)*8,
           ((unsigned short*)Kb) + (size_t)sbase*8);
  }
  // stage Qa (32 rows x 16 chunks = 512 slots), swizzled in global
  #pragma unroll
  for(int j=0;j<2;j++){
    int sbase = w*128 + j*64;
    GLDS16(qa_bf + (size_t)n0*D128 + (size_t)(sbase + l)*8,
           ((unsigned short*)Qa) + (size_t)sbase*8);
  }
  __syncthreads();
  f32x4 acc[2][2];   // [ksub][nsub]
  #pragma unroll
  for(int i=0;i<2;i++)
    #pragma unroll
    for(int j=0;j<2;j++)
      acc[i][j] = (f32x4){0.f,0.f,0.f,0.f};
  const int sz = l15 & 7;
  #pragma unroll
  for(int ds=0; ds<4; ds++){
    int c = (((ds*4 + g) ^ sz))*8;
    short8v a0 = *(const short8v*)&Kb[w*32 + l15][c];
    short8v a1 = *(const short8v*)&Kb[w*32 + 16 + l15][c];
    short8v b0 = *(const short8v*)&Qa[l15][c];
    short8v b1 = *(const short8v*)&Qa[16 + l15][c];
    acc[0][0] = __builtin_amdgcn_mfma_f32_16x16x32_bf16(a0, b0, acc[0][0], 0,0,0);
    acc[0][1] = __builtin_amdgcn_mfma_f32_16x16x32_bf16(a0, b1, acc[0][1], 0,0,0);
    acc[1][0] = __builtin_amdgcn_mfma_f32_16x16x32_bf16(a1, b0, acc[1][0], 0,0,0);
    acc[1][1] = __builtin_amdgcn_mfma_f32_16x16x32_bf16(a1, b1, acc[1][1], 0,0,0);
  }
  // per-n tile max; clamp to >=0 so poison/padding (negative) can never win
  // (true logits are sums of |q|*|kpot| > 0; uint order == float order for >=0)
  #pragma unroll
  for(int jn=0; jn<2; jn++){
    float m4 = 0.f;
    #pragma unroll
    for(int ks=0; ks<2; ks++)
      #pragma unroll
      for(int r=0; r<4; r++)
        m4 = fmaxf(m4, acc[ks][jn][r]);
    atomicMax(&mx[jn*16 + l15], __float_as_uint(m4));
  }
  __syncthreads();
  #pragma unroll
  for(int jn=0; jn<2; jn++){
    int n = jn*16 + l15;
    float thr = __uint_as_float(mx[n]) - 21.0f;
    #pragma unroll
    for(int ks=0; ks<2; ks++){
      #pragma unroll
      for(int r=0; r<4; r++){
        int k = k0 + w*32 + ks*16 + g*4 + r;
        float aw = acc[ks][jn][r];
        if(k < K && aw >= thr){
          int s = atomicAdd(&cnt[n], 1);
          if(s < TOPS){
            size_t o = ((size_t)(n0+n)*NT + ty)*TOPS + s;
            taw[o] = aw; tk[o] = k;
          }
        }
      }
    }
  }
}

// Per row: global max over candidates, exact fp32 logit recompute for survivors,
// softmax, and output accumulation from only those k's.
__global__ __launch_bounds__(256) void k_final(const float* __restrict__ q,
    const float* __restrict__ kabs, const float* __restrict__ vcm,
    const float* __restrict__ vsm, const float* __restrict__ rfrac,
    const int* __restrict__ kinv, const int* __restrict__ tk,
    const float* __restrict__ taw, float* __restrict__ out, int N, int K, int NT){
  const int rb = threadIdx.x >> 2;
  const int j  = threadIdx.x & 3;
  const int row = blockIdx.x*64 + rb;
  if(row >= N) return;
  const int NE = NT*TOPS;
  const float* trow = taw + (size_t)row*NE;
  const int*   krow = tk  + (size_t)row*NE;
  float m = -1e30f;
  for(int i=j; i<NE; i+=4) m = fmaxf(m, trow[i]);
  m = fmaxf(m, __shfl_xor(m,1)); m = fmaxf(m, __shfl_xor(m,2));
  __shared__ int lk[64][FCAP];
  __shared__ int lcnt[64];
  if(j==0) lcnt[rb] = 0;
  __syncthreads();
  for(int i=j; i<NE; i+=4){
    float aw = trow[i];
    if(aw >= m - 24.0f){
      int s = atomicAdd(&lcnt[rb], 1);
      if(s < FCAP) lk[rb][s] = krow[i];
    }
  }
  __syncthreads();
  int cn = min(lcnt[rb], FCAP);
  const float* qrow = q + (size_t)row*D128;
  float paw[FCAP];
  for(int e=0; e<cn; e++){
    int k = lk[rb][e];
    const float* ar = kabs + (size_t)k*D128;
    float p = 0.f;
    #pragma unroll
    for(int d=0; d<32; d+=4){
      int dd = j*32 + d;
      f4 qv = *(const f4*)(qrow+dd); f4 av = *(const f4*)(ar+dd);
      p = fmaf(fabsf(qv.x), av.x, p); p = fmaf(fabsf(qv.y), av.y, p);
      p = fmaf(fabsf(qv.z), av.z, p); p = fmaf(fabsf(qv.w), av.w, p);
    }
    p += __shfl_xor(p,1); p += __shfl_xor(p,2);
    paw[e] = p;
  }
  float m2 = -1e30f;
  for(int e=0;e<cn;e++) m2 = fmaxf(m2, paw[e]);
  float w[FCAP]; float Z = 0.f;
  for(int e=0;e<cn;e++){ w[e] = expf(paw[e]-m2); Z += w[e]; }
  float o[32];
  #pragma unroll
  for(int t=0;t<32;t++) o[t]=0.f;
  f4 rf = *(const f4*)(rfrac + (size_t)row*4);
  for(int e=0;e<cn;e++){
    float wn = w[e]/Z;
    if(wn < 1e-7f) continue;
    int k = lk[rb][e];
    float t = rf.x*(float)kinv[k*3] + rf.y*(float)kinv[k*3+1] + rf.z*(float)kinv[k*3+2];
    t -= floorf(t);
    float si = sinpif(2.0f*t), ci = cospif(2.0f*t);
    float wc = wn*ci, wsn = wn*si;
    const float* vcr = vcm + (size_t)k*D128 + j*32;
    const float* vsr = vsm + (size_t)k*D128 + j*32;
    #pragma unroll
    for(int d=0; d<32; d+=4){
      f4 a2 = *(const f4*)(vcr+d); f4 b2 = *(const f4*)(vsr+d);
      o[d]   = fmaf(wc, a2.x, fmaf(wsn, b2.x, o[d]));
      o[d+1] = fmaf(wc, a2.y, fmaf(wsn, b2.y, o[d+1]));
      o[d+2] = fmaf(wc, a2.z, fmaf(wsn, b2.z, o[d+2]));
      o[d+3] = fmaf(wc, a2.w, fmaf(wsn, b2.w, o[d+3]));
    }
  }
  float* orow = out + (size_t)row*D128 + j*32;
  #pragma unroll
  for(int d=0; d<32; d+=4)
    *(f4*)(orow+d) = make_float4(o[d], o[d+1], o[d+2], o[d+3]);
}

extern "C" void kernel_launch(void* const* d_in, const int* in_sizes, int n_in,
                              void* d_out, int out_size, void* d_ws, size_t ws_size,
                              hipStream_t stream){
  const float* q    = (const float*)d_in[0];
  const float* kvec = (const float*)d_in[1];
  const float* vvec = (const float*)d_in[2];
  const float* pos  = (const float*)d_in[3];
  const float* cell = (const float*)d_in[4];
  const int*   kfwd = (const int*)d_in[6];
  const int*   kinv = (const int*)d_in[7];
  const int N = in_sizes[3]/3;
  const int K = in_sizes[6]/3;
  const int NT = (K + SKT - 1)/SKT;
  const int KPAD = NT*SKT;
  const int KTILES = (K + KT - 1)/KT;

  float* ws = (float*)d_ws;
  size_t o = 0;
  float* rfrac    = ws + o; o += (size_t)N*4;
  float* pot4     = ws + o; o += (size_t)4*K*D128;
  float* kabs     = ws + o; o += (size_t)K*D128;
  float* vcm      = ws + o; o += (size_t)K*D128;
  float* vsm      = ws + o; o += (size_t)K*D128;
  unsigned short* kabs_swz = (unsigned short*)(ws + o); o += (size_t)KPAD*D128/2 + 4;
  unsigned short* qa_bf    = (unsigned short*)(ws + o); o += (size_t)N*D128/2 + 4;
  float* taw      = ws + o; o += (size_t)N*NT*TOPS;
  int*   tk       = (int*)(ws + o); o += (size_t)N*NT*TOPS;
  unsigned short* kvhT = (unsigned short*)(ws + o); o += (size_t)D128*N/2;
  unsigned short* kvlT = (unsigned short*)(ws + o); o += (size_t)D128*N/2;
  unsigned short* vvhT = (unsigned short*)(ws + o); o += (size_t)D128*N/2;
  float* out = (float*)d_out;

  k_prep<<<dim3((N+255)/256), dim3(256), 0, stream>>>(pos, cell, rfrac, N);
  k_zero<<<dim3(1024), dim3(256), 0, stream>>>(pot4, 4*K*D128);
  k_cvt<<<dim3(N/32), dim3(256), 0, stream>>>(q, kvec, vvec, kvhT, kvlT, vvhT, qa_bf, N);
  k_pot_mfma<<<dim3(KTILES, NSPLIT), dim3(512), 0, stream>>>(
      kvhT, kvlT, vvhT, rfrac, kfwd, pot4, N, K);
  k_merge<<<dim3((KPAD*D128 + 255)/256), dim3(256), 0, stream>>>(
      pot4, kabs, kabs_swz, vcm, vsm, K, KPAD);
  k_screen<<<dim3(N/SNR, NT), dim3(256), 0, stream>>>(qa_bf, kabs_swz, tk, taw, N, K, NT);
  k_final<<<dim3((N+63)/64), dim3(256), 0, stream>>>(
      q, kabs, vcm, vsm, rfrac, kinv, tk, taw, out, N, K, NT);
}

// Round 6
// 244.767 us; speedup vs baseline: 3.0725x; 1.1103x over previous
//
#include <hip/hip_runtime.h>
#include <hip/hip_bf16.h>

#define D128 128
#define NSPLIT 8
#define KT 64
#define SNR 32
#define SKT 128
#define TOPS 8
#define FCAP 16

typedef float4 f4;
typedef __attribute__((ext_vector_type(8))) short short8v;
typedef __attribute__((ext_vector_type(4))) float f32x4;

__device__ __forceinline__ unsigned short f2bu(float x){
  __hip_bfloat16 h = __float2bfloat16(x);
  return *(unsigned short*)&h;
}
__device__ __forceinline__ float bu2f(unsigned short u){
  return __uint_as_float(((unsigned)u) << 16);
}

#define GLDS16(gp, lp) __builtin_amdgcn_global_load_lds( \
    (const __attribute__((address_space(1))) unsigned int*)(const void*)(gp), \
    (__attribute__((address_space(3))) unsigned int*)(lp), 16, 0, 0)

// zero the pot4 accumulator (ws is poisoned 0xAA before every launch)
__global__ __launch_bounds__(256) void k_zero(float* __restrict__ p, int total){
  int i = blockIdx.x*256 + threadIdx.x;
  int stride = gridDim.x*256;
  for(; i < total; i += stride) p[i] = 0.f;
}

// Fused: rfrac = pos/box; transpose + bf16-split k_vector/v_vector into
// [d][atom]; |q| bf16 row-major with chunk-XOR swizzle baked into global layout.
__global__ __launch_bounds__(256) void k_cvt(const float* __restrict__ pos,
    const float* __restrict__ cell, float* __restrict__ rfrac,
    const float* __restrict__ q, const float* __restrict__ kvec,
    const float* __restrict__ vvec, unsigned short* __restrict__ kvhT,
    unsigned short* __restrict__ kvlT, unsigned short* __restrict__ vvhT,
    unsigned short* __restrict__ qa_bf, int N){
  __shared__ float sk[32][132], sv[32][132];
  const int tid = threadIdx.x;
  const int c0 = blockIdx.x*32;
  if(tid < 32){
    int i = c0 + tid;
    float bx = cell[0], by = cell[4], bz = cell[8];
    f4 r; r.x = pos[i*3+0]/bx; r.y = pos[i*3+1]/by; r.z = pos[i*3+2]/bz; r.w = 0.f;
    ((f4*)rfrac)[i] = r;
  }
  #pragma unroll
  for(int i=0;i<2;i++){
    int idx = tid + i*256;            // 512 tasks: 32 rows x 16 chunks
    int row = idx >> 4, c = idx & 15;
    const float* src = q + (size_t)(c0+row)*D128 + c*8;
    f4 v0 = *(const f4*)src, v1 = *(const f4*)(src+4);
    uint4 o;
    o.x = (unsigned)f2bu(fabsf(v0.x)) | ((unsigned)f2bu(fabsf(v0.y))<<16);
    o.y = (unsigned)f2bu(fabsf(v0.z)) | ((unsigned)f2bu(fabsf(v0.w))<<16);
    o.z = (unsigned)f2bu(fabsf(v1.x)) | ((unsigned)f2bu(fabsf(v1.y))<<16);
    o.w = (unsigned)f2bu(fabsf(v1.z)) | ((unsigned)f2bu(fabsf(v1.w))<<16);
    *(uint4*)(qa_bf + (size_t)(c0+row)*D128 + ((c ^ (row&7))<<3)) = o;
  }
  #pragma unroll
  for(int i=0;i<4;i++){
    int idx = tid + i*256;            // 1024 f4-loads: 32 atoms x 32 quads
    int a = idx >> 5, fq = idx & 31;
    f4 v = ((const f4*)(kvec + (size_t)(c0+a)*D128))[fq];
    *(f4*)&sk[a][fq*4] = v;
    f4 u = ((const f4*)(vvec + (size_t)(c0+a)*D128))[fq];
    *(f4*)&sv[a][fq*4] = u;
  }
  __syncthreads();
  #pragma unroll
  for(int i=0;i<4;i++){
    int idx = tid + i*256;            // 1024 quad-items: 128 d x 8 atom-quads
    int d = idx >> 3, aq = idx & 7;
    size_t ob = (size_t)d*N + c0 + aq*4;
    ushort4 h, l, vh;
    float x0 = sk[aq*4+0][d], x1 = sk[aq*4+1][d], x2 = sk[aq*4+2][d], x3 = sk[aq*4+3][d];
    h.x = f2bu(x0); h.y = f2bu(x1); h.z = f2bu(x2); h.w = f2bu(x3);
    l.x = f2bu(x0 - bu2f(h.x)); l.y = f2bu(x1 - bu2f(h.y));
    l.z = f2bu(x2 - bu2f(h.z)); l.w = f2bu(x3 - bu2f(h.w));
    vh.x = f2bu(sv[aq*4+0][d]); vh.y = f2bu(sv[aq*4+1][d]);
    vh.z = f2bu(sv[aq*4+2][d]); vh.w = f2bu(sv[aq*4+3][d]);
    *(ushort4*)(kvhT + ob) = h;
    *(ushort4*)(kvlT + ob) = l;
    *(ushort4*)(vvhT + ob) = vh;
  }
}

// MFMA structure factors, 2-phase pipelined, chunk-XOR swizzled LDS, hw trig.
// Block: 64 k x D=128, N/NSPLIT atoms. 8 waves, wave w owns d-tile [w*16,+16).
__global__ __launch_bounds__(512) void k_pot_mfma(
    const unsigned short* __restrict__ kvhT, const unsigned short* __restrict__ kvlT,
    const unsigned short* __restrict__ vvhT, const float* __restrict__ rfrac,
    const int* __restrict__ kfwd, float* __restrict__ pot4, int N, int K){
  const int tid = threadIdx.x;
  const int k0 = blockIdx.x*KT;
  const int split = blockIdx.y;
  const int part = N/NSPLIT;
  const int abase = split*part;
  __shared__ unsigned short Ae[2][4][KT][32];    // 32 KB: [buf][ech,ecl,esh,esl][k][atom-swz]
  __shared__ unsigned short Bl[2][3][D128][32];  // 48 KB: [buf][kvh,kvl,vvh][d][atom-swz]
  const int w = tid >> 6, l = tid & 63, l15 = l & 15, g = l >> 4;
  // E-gen mapping: 2 k x 2 atoms per thread
  const int kp = tid >> 4;          // 0..31 -> k pair base
  const int a0 = (tid & 15)*2;      // even atom base
  float kfa[2][3];
  {
    int r0 = min(k0 + kp*2,     K-1);
    int r1 = min(k0 + kp*2 + 1, K-1);
    kfa[0][0] = (float)kfwd[3*r0]; kfa[0][1] = (float)kfwd[3*r0+1]; kfa[0][2] = (float)kfwd[3*r0+2];
    kfa[1][0] = (float)kfwd[3*r1]; kfa[1][1] = (float)kfwd[3*r1+1]; kfa[1][2] = (float)kfwd[3*r1+2];
  }
  f32x4 acc[4][4];   // [ksub][kc,ks,vc,vs]
  #pragma unroll
  for(int i=0;i<4;i++)
    #pragma unroll
    for(int j=0;j<4;j++)
      acc[i][j] = (f32x4){0.f,0.f,0.f,0.f};
  const int rowS = w*16 + (l >> 2);                 // staging row (d)
  const int csrc = (((l & 3) ^ ((l >> 3) & 3)))*8;  // source chunk (inv-swizzle)
  const int cA   = (g ^ ((l15 >> 1) & 3))*8;        // read chunk (swizzled)

  auto stage = [&](int buf, int c0a){
    size_t goff = (size_t)rowS*N + c0a + csrc;
    GLDS16(kvhT + goff, &Bl[buf][0][w*16][0]);
    GLDS16(kvlT + goff, &Bl[buf][1][w*16][0]);
    GLDS16(vvhT + goff, &Bl[buf][2][w*16][0]);
  };
  auto egen = [&](int buf, int c0a){
    f4 r0 = ((const f4*)rfrac)[c0a + a0];
    f4 r1 = ((const f4*)rfrac)[c0a + a0 + 1];
    #pragma unroll
    for(int kk=0; kk<2; kk++){
      int kloc = kp*2 + kk;
      float t0 = __builtin_amdgcn_fractf(r0.x*kfa[kk][0] + r0.y*kfa[kk][1] + r0.z*kfa[kk][2]);
      float t1 = __builtin_amdgcn_fractf(r1.x*kfa[kk][0] + r1.y*kfa[kk][1] + r1.z*kfa[kk][2]);
      float c0v = __builtin_amdgcn_cosf(t0), s0v = __builtin_amdgcn_sinf(t0);
      float c1v = __builtin_amdgcn_cosf(t1), s1v = __builtin_amdgcn_sinf(t1);
      unsigned cb0 = __float_as_uint(c0v), cb1 = __float_as_uint(c1v);
      unsigned sb0 = __float_as_uint(s0v), sb1 = __float_as_uint(s1v);
      unsigned chp = (cb0 >> 16) | (cb1 & 0xffff0000u);
      unsigned shp = (sb0 >> 16) | (sb1 & 0xffff0000u);
      float cl0 = c0v - __uint_as_float(cb0 & 0xffff0000u);
      float cl1 = c1v - __uint_as_float(cb1 & 0xffff0000u);
      float sl0 = s0v - __uint_as_float(sb0 & 0xffff0000u);
      float sl1 = s1v - __uint_as_float(sb1 & 0xffff0000u);
      unsigned clp = (unsigned)f2bu(cl0) | ((unsigned)f2bu(cl1) << 16);
      unsigned slp = (unsigned)f2bu(sl0) | ((unsigned)f2bu(sl1) << 16);
      int off = (((a0>>3) ^ ((kloc>>1)&3)) << 3) | (a0 & 7);   // shorts, even
      *(unsigned*)&Ae[buf][0][kloc][off] = chp;
      *(unsigned*)&Ae[buf][1][kloc][off] = clp;
      *(unsigned*)&Ae[buf][2][kloc][off] = shp;
      *(unsigned*)&Ae[buf][3][kloc][off] = slp;
    }
  };

  stage(0, abase); egen(0, abase);
  __syncthreads();
  const int nch = part/32;
  for(int ch=0; ch<nch; ch++){
    int cur = ch & 1;
    if(ch+1 < nch){ stage(cur^1, abase + (ch+1)*32); egen(cur^1, abase + (ch+1)*32); }
    short8v bKh = *(const short8v*)&Bl[cur][0][w*16 + l15][cA];
    short8v bKl = *(const short8v*)&Bl[cur][1][w*16 + l15][cA];
    short8v bVh = *(const short8v*)&Bl[cur][2][w*16 + l15][cA];
    #pragma unroll
    for(int ks=0; ks<4; ks++){
      short8v e0 = *(const short8v*)&Ae[cur][0][ks*16 + l15][cA];
      short8v e1 = *(const short8v*)&Ae[cur][1][ks*16 + l15][cA];
      short8v e2 = *(const short8v*)&Ae[cur][2][ks*16 + l15][cA];
      short8v e3 = *(const short8v*)&Ae[cur][3][ks*16 + l15][cA];
      acc[ks][0] = __builtin_amdgcn_mfma_f32_16x16x32_bf16(e0, bKh, acc[ks][0], 0,0,0);
      acc[ks][1] = __builtin_amdgcn_mfma_f32_16x16x32_bf16(e2, bKh, acc[ks][1], 0,0,0);
      acc[ks][2] = __builtin_amdgcn_mfma_f32_16x16x32_bf16(e0, bVh, acc[ks][2], 0,0,0);
      acc[ks][3] = __builtin_amdgcn_mfma_f32_16x16x32_bf16(e2, bVh, acc[ks][3], 0,0,0);
      acc[ks][0] = __builtin_amdgcn_mfma_f32_16x16x32_bf16(e0, bKl, acc[ks][0], 0,0,0);
      acc[ks][1] = __builtin_amdgcn_mfma_f32_16x16x32_bf16(e2, bKl, acc[ks][1], 0,0,0);
      acc[ks][0] = __builtin_amdgcn_mfma_f32_16x16x32_bf16(e1, bKh, acc[ks][0], 0,0,0);
      acc[ks][1] = __builtin_amdgcn_mfma_f32_16x16x32_bf16(e3, bKh, acc[ks][1], 0,0,0);
    }
    __syncthreads();
  }
  // epilogue: C/D layout col=lane&15 (d), row=(lane>>4)*4+reg (k)
  size_t M = (size_t)K*D128;
  #pragma unroll
  for(int ks=0; ks<4; ks++){
    #pragma unroll
    for(int reg=0; reg<4; reg++){
      int k = k0 + ks*16 + g*4 + reg;
      if(k < K){
        int d = w*16 + l15;
        size_t base = (size_t)k*D128 + d;
        atomicAdd(&pot4[base],       acc[ks][0][reg]);
        atomicAdd(&pot4[base + M],   acc[ks][1][reg]);
        atomicAdd(&pot4[base + 2*M], acc[ks][2][reg]);
        atomicAdd(&pot4[base + 3*M], acc[ks][3][reg]);
      }
    }
  }
}

// Emit |k_pot| (fp32 exact + bf16 swizzled) and Re/Im(v_pot); zero padding rows.
__global__ __launch_bounds__(256) void k_merge(const float* __restrict__ pot4,
    float* __restrict__ kabs, unsigned short* __restrict__ kabs_swz,
    float* __restrict__ vcm, float* __restrict__ vsm, int K, int KPAD){
  size_t M = (size_t)K*D128;
  size_t idx = (size_t)blockIdx.x*256 + threadIdx.x;
  if(idx >= (size_t)KPAD*D128) return;
  int k = (int)(idx >> 7), d = (int)(idx & 127);
  size_t sw = (size_t)k*D128 + ((((d>>3) ^ (k&7))<<3) | (d&7));
  if(idx < M){
    float kc = pot4[idx], ks_ = pot4[M+idx], vc = pot4[2*M+idx], vs = pot4[3*M+idx];
    float ab = sqrtf(fmaf(kc,kc, ks_*ks_));
    kabs[idx] = ab;
    vcm[idx] = vc; vsm[idx] = vs;
    kabs_swz[sw] = f2bu(ab);
  } else {
    kabs_swz[sw] = 0;
  }
}

// Screen GEMM via bf16 MFMA: aw[n,k] = sum_d |q|*|k_pot|.
// Block: 32 n-rows x 128 k. 4 waves, wave w owns k-block [w*32,+32).
// Emits per (row, 128-k tile) the top-8 entries within 21 of the tile max.
__global__ __launch_bounds__(256) void k_screen(
    const unsigned short* __restrict__ qa_bf, const unsigned short* __restrict__ kabs_swz,
    int* __restrict__ tk, float* __restrict__ taw, int N, int K, int NT){
  const int tid = threadIdx.x;
  const int w = tid >> 6, l = tid & 63, l15 = l & 15, g = l >> 4;
  const int n0 = blockIdx.x*SNR;
  const int ty = blockIdx.y;
  const int k0 = ty*SKT;
  __shared__ unsigned short Kb[SKT][D128];
  __shared__ unsigned short Qa[SNR][D128];
  __shared__ int cnt[SNR];
  __shared__ unsigned mx[SNR];
  if(tid < SNR){ cnt[tid] = 0; mx[tid] = 0u; }
  {
    int row = tid >> 3, s = tid & 7;
    size_t o = ((size_t)(n0+row)*NT + ty)*TOPS + s;
    taw[o] = -1e30f; tk[o] = -1;
  }
  #pragma unroll
  for(int j=0;j<8;j++){
    int sbase = w*512 + j*64;
    GLDS16(kabs_swz + (size_t)k0*D128 + (size_t)(sbase + l)*8,
           ((unsigned short*)Kb) + (size_t)sbase*8);
  }
  #pragma unroll
  for(int j=0;j<2;j++){
    int sbase = w*128 + j*64;
    GLDS16(qa_bf + (size_t)n0*D128 + (size_t)(sbase + l)*8,
           ((unsigned short*)Qa) + (size_t)sbase*8);
  }
  __syncthreads();
  f32x4 acc[2][2];   // [ksub][nsub]
  #pragma unroll
  for(int i=0;i<2;i++)
    #pragma unroll
    for(int j=0;j<2;j++)
      acc[i][j] = (f32x4){0.f,0.f,0.f,0.f};
  const int sz = l15 & 7;
  #pragma unroll
  for(int ds=0; ds<4; ds++){
    int c = (((ds*4 + g) ^ sz))*8;
    short8v a0 = *(const short8v*)&Kb[w*32 + l15][c];
    short8v a1 = *(const short8v*)&Kb[w*32 + 16 + l15][c];
    short8v b0 = *(const short8v*)&Qa[l15][c];
    short8v b1 = *(const short8v*)&Qa[16 + l15][c];
    acc[0][0] = __builtin_amdgcn_mfma_f32_16x16x32_bf16(a0, b0, acc[0][0], 0,0,0);
    acc[0][1] = __builtin_amdgcn_mfma_f32_16x16x32_bf16(a0, b1, acc[0][1], 0,0,0);
    acc[1][0] = __builtin_amdgcn_mfma_f32_16x16x32_bf16(a1, b0, acc[1][0], 0,0,0);
    acc[1][1] = __builtin_amdgcn_mfma_f32_16x16x32_bf16(a1, b1, acc[1][1], 0,0,0);
  }
  // per-n tile max; clamp to >=0 so padding can never win (uint order == float order for >=0)
  #pragma unroll
  for(int jn=0; jn<2; jn++){
    float m4 = 0.f;
    #pragma unroll
    for(int ks=0; ks<2; ks++)
      #pragma unroll
      for(int r=0; r<4; r++)
        m4 = fmaxf(m4, acc[ks][jn][r]);
    atomicMax(&mx[jn*16 + l15], __float_as_uint(m4));
  }
  __syncthreads();
  #pragma unroll
  for(int jn=0; jn<2; jn++){
    int n = jn*16 + l15;
    float thr = __uint_as_float(mx[n]) - 21.0f;
    #pragma unroll
    for(int ks=0; ks<2; ks++){
      #pragma unroll
      for(int r=0; r<4; r++){
        int k = k0 + w*32 + ks*16 + g*4 + r;
        float aw = acc[ks][jn][r];
        if(k < K && aw >= thr){
          int s = atomicAdd(&cnt[n], 1);
          if(s < TOPS){
            size_t o = ((size_t)(n0+n)*NT + ty)*TOPS + s;
            taw[o] = aw; tk[o] = k;
          }
        }
      }
    }
  }
}

// Per row: global max over candidates, exact fp32 logit recompute for survivors,
// softmax, and output accumulation from only those k's.
__global__ __launch_bounds__(256) void k_final(const float* __restrict__ q,
    const float* __restrict__ kabs, const float* __restrict__ vcm,
    const float* __restrict__ vsm, const float* __restrict__ rfrac,
    const int* __restrict__ kinv, const int* __restrict__ tk,
    const float* __restrict__ taw, float* __restrict__ out, int N, int K, int NT){
  const int rb = threadIdx.x >> 2;
  const int j  = threadIdx.x & 3;
  const int row = blockIdx.x*64 + rb;
  if(row >= N) return;
  const int NE = NT*TOPS;
  const float* trow = taw + (size_t)row*NE;
  const int*   krow = tk  + (size_t)row*NE;
  float m = -1e30f;
  for(int i=j; i<NE; i+=4) m = fmaxf(m, trow[i]);
  m = fmaxf(m, __shfl_xor(m,1)); m = fmaxf(m, __shfl_xor(m,2));
  __shared__ int lk[64][FCAP];
  __shared__ int lcnt[64];
  if(j==0) lcnt[rb] = 0;
  __syncthreads();
  for(int i=j; i<NE; i+=4){
    float aw = trow[i];
    if(aw >= m - 24.0f){
      int s = atomicAdd(&lcnt[rb], 1);
      if(s < FCAP) lk[rb][s] = krow[i];
    }
  }
  __syncthreads();
  int cn = min(lcnt[rb], FCAP);
  const float* qrow = q + (size_t)row*D128;
  float paw[FCAP];
  for(int e=0; e<cn; e++){
    int k = lk[rb][e];
    const float* ar = kabs + (size_t)k*D128;
    float p = 0.f;
    #pragma unroll
    for(int d=0; d<32; d+=4){
      int dd = j*32 + d;
      f4 qv = *(const f4*)(qrow+dd); f4 av = *(const f4*)(ar+dd);
      p = fmaf(fabsf(qv.x), av.x, p); p = fmaf(fabsf(qv.y), av.y, p);
      p = fmaf(fabsf(qv.z), av.z, p); p = fmaf(fabsf(qv.w), av.w, p);
    }
    p += __shfl_xor(p,1); p += __shfl_xor(p,2);
    paw[e] = p;
  }
  float m2 = -1e30f;
  for(int e=0;e<cn;e++) m2 = fmaxf(m2, paw[e]);
  float w[FCAP]; float Z = 0.f;
  for(int e=0;e<cn;e++){ w[e] = expf(paw[e]-m2); Z += w[e]; }
  float o[32];
  #pragma unroll
  for(int t=0;t<32;t++) o[t]=0.f;
  f4 rf = *(const f4*)(rfrac + (size_t)row*4);
  for(int e=0;e<cn;e++){
    float wn = w[e]/Z;
    if(wn < 1e-7f) continue;
    int k = lk[rb][e];
    float t = __builtin_amdgcn_fractf(rf.x*(float)kinv[k*3] + rf.y*(float)kinv[k*3+1] + rf.z*(float)kinv[k*3+2]);
    float si = __builtin_amdgcn_sinf(t), ci = __builtin_amdgcn_cosf(t);
    float wc = wn*ci, wsn = wn*si;
    const float* vcr = vcm + (size_t)k*D128 + j*32;
    const float* vsr = vsm + (size_t)k*D128 + j*32;
    #pragma unroll
    for(int d=0; d<32; d+=4){
      f4 a2 = *(const f4*)(vcr+d); f4 b2 = *(const f4*)(vsr+d);
      o[d]   = fmaf(wc, a2.x, fmaf(wsn, b2.x, o[d]));
      o[d+1] = fmaf(wc, a2.y, fmaf(wsn, b2.y, o[d+1]));
      o[d+2] = fmaf(wc, a2.z, fmaf(wsn, b2.z, o[d+2]));
      o[d+3] = fmaf(wc, a2.w, fmaf(wsn, b2.w, o[d+3]));
    }
  }
  float* orow = out + (size_t)row*D128 + j*32;
  #pragma unroll
  for(int d=0; d<32; d+=4)
    *(f4*)(orow+d) = make_float4(o[d], o[d+1], o[d+2], o[d+3]);
}

extern "C" void kernel_launch(void* const* d_in, const int* in_sizes, int n_in,
                              void* d_out, int out_size, void* d_ws, size_t ws_size,
                              hipStream_t stream){
  const float* q    = (const float*)d_in[0];
  const float* kvec = (const float*)d_in[1];
  const float* vvec = (const float*)d_in[2];
  const float* pos  = (const float*)d_in[3];
  const float* cell = (const float*)d_in[4];
  const int*   kfwd = (const int*)d_in[6];
  const int*   kinv = (const int*)d_in[7];
  const int N = in_sizes[3]/3;
  const int K = in_sizes[6]/3;
  const int NT = (K + SKT - 1)/SKT;
  const int KPAD = NT*SKT;
  const int KTILES = (K + KT - 1)/KT;

  float* ws = (float*)d_ws;
  size_t o = 0;
  float* rfrac    = ws + o; o += (size_t)N*4;
  float* pot4     = ws + o; o += (size_t)4*K*D128;
  float* kabs     = ws + o; o += (size_t)K*D128;
  float* vcm      = ws + o; o += (size_t)K*D128;
  float* vsm      = ws + o; o += (size_t)K*D128;
  unsigned short* kabs_swz = (unsigned short*)(ws + o); o += (size_t)KPAD*D128/2 + 4;
  unsigned short* qa_bf    = (unsigned short*)(ws + o); o += (size_t)N*D128/2 + 4;
  float* taw      = ws + o; o += (size_t)N*NT*TOPS;
  int*   tk       = (int*)(ws + o); o += (size_t)N*NT*TOPS;
  unsigned short* kvhT = (unsigned short*)(ws + o); o += (size_t)D128*N/2;
  unsigned short* kvlT = (unsigned short*)(ws + o); o += (size_t)D128*N/2;
  unsigned short* vvhT = (unsigned short*)(ws + o); o += (size_t)D128*N/2;
  float* out = (float*)d_out;

  k_zero<<<dim3(1024), dim3(256), 0, stream>>>(pot4, 4*K*D128);
  k_cvt<<<dim3(N/32), dim3(256), 0, stream>>>(pos, cell, rfrac, q, kvec, vvec,
      kvhT, kvlT, vvhT, qa_bf, N);
  k_pot_mfma<<<dim3(KTILES, NSPLIT), dim3(512), 0, stream>>>(
      kvhT, kvlT, vvhT, rfrac, kfwd, pot4, N, K);
  k_merge<<<dim3((KPAD*D128 + 255)/256), dim3(256), 0, stream>>>(
      pot4, kabs, kabs_swz, vcm, vsm, K, KPAD);
  k_screen<<<dim3(N/SNR, NT), dim3(256), 0, stream>>>(qa_bf, kabs_swz, tk, taw, N, K, NT);
  k_final<<<dim3((N+63)/64), dim3(256), 0, stream>>>(
      q, kabs, vcm, vsm, rfrac, kinv, tk, taw, out, N, K, NT);
}